// Round 8
// baseline (206.734 us; speedup 1.0000x reference)
//
#include <hip/hip_runtime.h>

// Problem constants
constexpr int Bz  = 8;
constexpr int Lz  = 512;
constexpr int Hz  = 256;
constexpr int H2z = 512;
constexpr int Vz  = 32000;
constexpr int Mz  = Bz * Lz;      // 4096 tokens
constexpr float CF = 0.05f;       // 1 - ALPHA
constexpr int NB  = 16;           // 16 blocks of 32 = 512 (511 real + 1 dummy)

typedef __attribute__((ext_vector_type(8))) short bfrag8;   // 8 bf16
typedef __attribute__((ext_vector_type(4))) float f32x4v;
typedef __attribute__((ext_vector_type(4))) short s4v;

static __device__ __forceinline__ short f2bf(float f) {
  unsigned u = __builtin_bit_cast(unsigned, f);
  u += 0x7fffu + ((u >> 16) & 1u);           // round-to-nearest-even
  return (short)(u >> 16);
}

// ---------------------------------------------------------------------------
// Weight transpose+convert, both W1 and W2 in one launch. dst[n][k]=bf16(src[k][n])
// ---------------------------------------------------------------------------
static __device__ __forceinline__ void wcvt_tile(
    const float* __restrict__ src, short* __restrict__ dst,
    int K, int N, int n0, int k0, int tid)
{
  __shared__ float tile[64][68];
  const int rr = tid >> 4, c4 = (tid & 15) << 2;
#pragma unroll
  for (int q = 0; q < 4; ++q) {
    const int kr = rr + q * 16;
    *(float4*)&tile[kr][c4] = *(const float4*)(src + (long)(k0 + kr) * N + n0 + c4);
  }
  __syncthreads();
#pragma unroll
  for (int q = 0; q < 4; ++q) {
    const int nr = rr + q * 16;
    s4v o = { f2bf(tile[c4 + 0][nr]), f2bf(tile[c4 + 1][nr]),
              f2bf(tile[c4 + 2][nr]), f2bf(tile[c4 + 3][nr]) };
    *(s4v*)(dst + (long)(n0 + nr) * K + k0 + c4) = o;
  }
}

__global__ __launch_bounds__(256) void k_wcvt2(
    const float* __restrict__ W1, const float* __restrict__ W2,
    short* __restrict__ Wt1, short* __restrict__ Wt2)
{
  const int bx = blockIdx.x, tid = threadIdx.x;
  if (bx < 32) {
    wcvt_tile(W1, Wt1, Hz, H2z, (bx & 7) * 64, (bx >> 3) * 64, tid);
  } else {
    const int b2 = bx - 32;
    wcvt_tile(W2, Wt2, H2z, Hz, (b2 & 3) * 64, (b2 >> 2) * 64, tid);
  }
}

// ---------------------------------------------------------------------------
// MFMA GEMM1 with fused embedding gather:
// y1bf[4096,512] = bf16(relu(bf16(embed[seq]) @ Wt1^T + b1))
// ---------------------------------------------------------------------------
__global__ __launch_bounds__(256) void k_mfma1(
    const int* __restrict__ seq, const float* __restrict__ embed,
    const short* __restrict__ Wt1, const float* __restrict__ b1,
    short* __restrict__ y1bf)
{
  __shared__ short As[64][32];
  __shared__ short Bs[64][32];
  const int tid = threadIdx.x;
  const int n0 = blockIdx.x * 64, m0 = blockIdx.y * 64;
  const int w = tid >> 6, l = tid & 63;
  const int srow = tid >> 2, skq = (tid & 3) << 3;
  const long abase = (long)seq[m0 + srow] * Hz;
  const f32x4v zero = {0.f, 0.f, 0.f, 0.f};
  f32x4v acc[4] = {zero, zero, zero, zero};
  for (int kc = 0; kc < Hz; kc += 32) {
    const float4 a0 = *(const float4*)(embed + abase + kc + skq);
    const float4 a1 = *(const float4*)(embed + abase + kc + skq + 4);
    const bfrag8 bvl = *(const bfrag8*)(Wt1 + (long)(n0 + srow) * Hz + kc + skq);
    __syncthreads();
    bfrag8 av = { f2bf(a0.x), f2bf(a0.y), f2bf(a0.z), f2bf(a0.w),
                  f2bf(a1.x), f2bf(a1.y), f2bf(a1.z), f2bf(a1.w) };
    *(bfrag8*)&As[srow][skq] = av;
    *(bfrag8*)&Bs[srow][skq] = bvl;
    __syncthreads();
    const bfrag8 a = *(const bfrag8*)&As[(w << 4) + (l & 15)][(l >> 4) << 3];
#pragma unroll
    for (int nn = 0; nn < 4; ++nn) {
      const bfrag8 bb = *(const bfrag8*)&Bs[(nn << 4) + (l & 15)][(l >> 4) << 3];
      acc[nn] = __builtin_amdgcn_mfma_f32_16x16x32_bf16(a, bb, acc[nn], 0, 0, 0);
    }
  }
  const int col0 = l & 15, quad = l >> 4;
#pragma unroll
  for (int nn = 0; nn < 4; ++nn) {
    const int col = n0 + (nn << 4) + col0;
    const float bias = b1[col];
#pragma unroll
    for (int i = 0; i < 4; ++i) {
      const int row = m0 + (w << 4) + (quad << 2) + i;
      y1bf[(long)row * H2z + col] = f2bf(fmaxf(acc[nn][i] + bias, 0.0f));
    }
  }
}

// ---------------------------------------------------------------------------
// MFMA GEMM2: x[4096,256] = y1bf @ Wt2^T + b2 + embed[seq]  (fp32 out)
// ---------------------------------------------------------------------------
__global__ __launch_bounds__(256) void k_mfma2(
    const int* __restrict__ seq, const float* __restrict__ embed,
    const short* __restrict__ y1bf, const short* __restrict__ Wt2,
    const float* __restrict__ b2, float* __restrict__ x)
{
  __shared__ short As[64][32];
  __shared__ short Bs[64][32];
  const int tid = threadIdx.x;
  const int n0 = blockIdx.x * 64, m0 = blockIdx.y * 64;
  const int w = tid >> 6, l = tid & 63;
  const int srow = tid >> 2, skq = (tid & 3) << 3;
  const f32x4v zero = {0.f, 0.f, 0.f, 0.f};
  f32x4v acc[4] = {zero, zero, zero, zero};
  for (int kc = 0; kc < H2z; kc += 32) {
    __syncthreads();
    *(bfrag8*)&As[srow][skq] = *(const bfrag8*)(y1bf + (long)(m0 + srow) * H2z + kc + skq);
    *(bfrag8*)&Bs[srow][skq] = *(const bfrag8*)(Wt2 + (long)(n0 + srow) * H2z + kc + skq);
    __syncthreads();
    const bfrag8 a = *(const bfrag8*)&As[(w << 4) + (l & 15)][(l >> 4) << 3];
#pragma unroll
    for (int nn = 0; nn < 4; ++nn) {
      const bfrag8 bb = *(const bfrag8*)&Bs[(nn << 4) + (l & 15)][(l >> 4) << 3];
      acc[nn] = __builtin_amdgcn_mfma_f32_16x16x32_bf16(a, bb, acc[nn], 0, 0, 0);
    }
  }
  const int col0 = l & 15, quad = l >> 4;
#pragma unroll
  for (int i = 0; i < 4; ++i) {
    const int row = m0 + (w << 4) + (quad << 2) + i;
    const long ebase = (long)seq[row] * Hz;
#pragma unroll
    for (int nn = 0; nn < 4; ++nn) {
      const int col = n0 + (nn << 4) + col0;
      x[(long)row * Hz + col] = acc[nn][i] + b2[col] + embed[ebase + col];
    }
  }
}

// ---------------------------------------------------------------------------
// LayerNorm + L2-normalize; writes h (fp32, t-order), hn (fp32, t-order),
// and Knb (bf16, s-order: s = 510-t; row 511 zeroed dummy).
// ---------------------------------------------------------------------------
__global__ __launch_bounds__(256) void k_ln(
    const float* __restrict__ x, const float* __restrict__ gamma,
    const float* __restrict__ beta, float* __restrict__ h,
    float* __restrict__ hn, short* __restrict__ Knb)
{
  const int lane = threadIdx.x & 63;
  const long row = (long)blockIdx.x * 4 + (threadIdx.x >> 6);
  const int b = (int)(row >> 9), t = (int)(row & 511);
  const int off = lane << 2;
  const float4 xv = *(const float4*)(x + row * Hz + off);
  float s  = xv.x + xv.y + xv.z + xv.w;
  float ss = xv.x * xv.x + xv.y * xv.y + xv.z * xv.z + xv.w * xv.w;
#pragma unroll
  for (int o = 32; o >= 1; o >>= 1) { s += __shfl_xor(s, o); ss += __shfl_xor(ss, o); }
  const float mu   = s * (1.0f / Hz);
  const float var  = ss * (1.0f / Hz) - mu * mu;
  const float rstd = rsqrtf(var + 1e-5f);
  const float4 gv = *(const float4*)(gamma + off);
  const float4 bv = *(const float4*)(beta + off);
  float4 hv;
  hv.x = (xv.x - mu) * rstd * gv.x + bv.x;
  hv.y = (xv.y - mu) * rstd * gv.y + bv.y;
  hv.z = (xv.z - mu) * rstd * gv.z + bv.z;
  hv.w = (xv.w - mu) * rstd * gv.w + bv.w;
  *(float4*)(h + row * Hz + off) = hv;
  float hs = hv.x * hv.x + hv.y * hv.y + hv.z * hv.z + hv.w * hv.w;
#pragma unroll
  for (int o = 32; o >= 1; o >>= 1) hs += __shfl_xor(hs, o);
  const float inv = 1.0f / fmaxf(sqrtf(hs), 1e-12f);
  float4 nv = {hv.x * inv, hv.y * inv, hv.z * inv, hv.w * inv};
  *(float4*)(hn + row * Hz + off) = nv;
  if (t < 511) {
    const int sidx = 510 - t;
    s4v o = { f2bf(nv.x), f2bf(nv.y), f2bf(nv.z), f2bf(nv.w) };
    *(s4v*)(Knb + ((long)b * 512 + sidx) * Hz + off) = o;
  } else {
    s4v z = {0, 0, 0, 0};
    *(s4v*)(Knb + ((long)b * 512 + 511) * Hz + off) = z;
  }
}

// ---------------------------------------------------------------------------
// Full Gram via bf16 MFMA (lower tiles), with FUSED block-diag inverse:
// diagonal-tile WGs stage their two 32x32 diag blocks to LDS and one wave per
// block computes W = (I+CF*L)^{-1} via fully-unrolled single-wave forward
// substitution (lane = column; zero barriers, zero cross-lane ops).
// ---------------------------------------------------------------------------
__global__ __launch_bounds__(256) void k_gramT(
    const short* __restrict__ Knb, float* __restrict__ G,
    float* __restrict__ Wsol)
{
  const int nb = blockIdx.x, mb = blockIdx.y, b = blockIdx.z;
  if (nb > mb) return;
  __shared__ short As[64][32];
  __shared__ short Bs[64][32];
  __shared__ float Gs2[2][32][33];
  const short* Kb = Knb + (long)b * 512 * Hz;
  const int tid = threadIdx.x;
  const int w = tid >> 6, l = tid & 63;
  const int srow = tid >> 2, skq = (tid & 3) << 3;
  const f32x4v zero = {0.f, 0.f, 0.f, 0.f};
  f32x4v acc[4] = {zero, zero, zero, zero};
  for (int kc = 0; kc < Hz; kc += 32) {
    __syncthreads();
    *(bfrag8*)&As[srow][skq] = *(const bfrag8*)(Kb + (long)(mb * 64 + srow) * Hz + kc + skq);
    *(bfrag8*)&Bs[srow][skq] = *(const bfrag8*)(Kb + (long)(nb * 64 + srow) * Hz + kc + skq);
    __syncthreads();
    const bfrag8 a = *(const bfrag8*)&As[(w << 4) + (l & 15)][(l >> 4) << 3];
#pragma unroll
    for (int nn = 0; nn < 4; ++nn) {
      const bfrag8 bb = *(const bfrag8*)&Bs[(nn << 4) + (l & 15)][(l >> 4) << 3];
      acc[nn] = __builtin_amdgcn_mfma_f32_16x16x32_bf16(a, bb, acc[nn], 0, 0, 0);
    }
  }
  const int col0 = l & 15, quad = l >> 4;
  float* Gb = G + (long)b * 512 * 512;
#pragma unroll
  for (int nn = 0; nn < 4; ++nn) {
    const int col = nb * 64 + (nn << 4) + col0;
#pragma unroll
    for (int i = 0; i < 4; ++i) {
      const int row = mb * 64 + (w << 4) + (quad << 2) + i;
      Gb[(long)row * 512 + col] = acc[nn][i];
    }
  }
  if (mb != nb) return;
  // stage the two diagonal 32x32 blocks
#pragma unroll
  for (int nn = 0; nn < 4; ++nn) {
    const int lc = (nn << 4) + col0;
#pragma unroll
    for (int i = 0; i < 4; ++i) {
      const int lr = (w << 4) + (quad << 2) + i;
      if ((lr >> 5) == (lc >> 5)) Gs2[lr >> 5][lr & 31][lc & 31] = acc[nn][i];
    }
  }
  __syncthreads();
  if (w < 2 && l < 32) {       // wave w inverts sub-block w; lane = column c
    const int c = l;
    float wv[32];
    wv[0] = (c == 0) ? 1.0f : 0.0f;
#pragma unroll
    for (int i = 1; i < 32; ++i) {
      float sum = 0.0f;
#pragma unroll
      for (int j = 0; j < i; ++j) sum = fmaf(Gs2[w][i][j], wv[j], sum);
      wv[i] = ((i == c) ? 1.0f : 0.0f) - CF * sum;
    }
    const int blk = mb * 2 + w;
    float* dst = Wsol + ((long)(b * NB + blk) << 10) + c;
#pragma unroll
    for (int i = 0; i < 32; ++i) dst[i * 32] = wv[i];
  }
}

// ---------------------------------------------------------------------------
// Fused tail: p (paired-lane dots) -> 16-step block-triangular solve ->
// m accumulation -> r = m@Wrp + brp.  One WG (1024 thr) per batch.
// ---------------------------------------------------------------------------
__global__ __launch_bounds__(1024) void k_tail(
    const float* __restrict__ h, const float* __restrict__ hn,
    const float* __restrict__ G, const float* __restrict__ Wsol,
    const float* __restrict__ Wrp, const float* __restrict__ brp,
    float* __restrict__ r)
{
  __shared__ float Wl[16][32][32];   // 64 KB: all block inverses
  __shared__ float qs[256];
  __shared__ float ps[512];
  __shared__ float ds[512];
  __shared__ float part[32][33];
  __shared__ float rhs[32];
  __shared__ float pm[4][256];
  __shared__ float ms[256];
  const int b = blockIdx.x, tid = threadIdx.x;
  const float* hb  = h  + (long)b * Lz * Hz;
  const float* hnb = hn + (long)b * Lz * Hz;
  const float* Gb  = G + (long)b * 512 * 512;

  if (tid < 256) qs[tid] = hb[511 * Hz + tid];
  {  // preload all 16 W-inverse blocks (16K floats / 1024 thr = 4 float4)
    const float4* src = (const float4*)(Wsol + ((long)(b * NB) << 10));
    float4* dst = (float4*)&Wl[0][0][0];
#pragma unroll
    for (int q = 0; q < 4; ++q) dst[tid + q * 1024] = src[tid + q * 1024];
  }
  __syncthreads();

  {  // p[s] = hn[510-s] . q  — 2 threads per s, combine via lane-pair shfl
    const int s = tid >> 1, hf = tid & 1;
    float acc = 0.0f;
    if (s < 511) {
      const float* src = hnb + (long)(510 - s) * Hz + hf * 128;
#pragma unroll
      for (int q = 0; q < 32; ++q) {
        const float4 v = *(const float4*)(src + 4 * q);
        const int e = hf * 128 + 4 * q;
        acc += v.x * qs[e] + v.y * qs[e + 1] + v.z * qs[e + 2] + v.w * qs[e + 3];
      }
    }
    acc += __shfl_xor(acc, 1);
    if (hf == 0) ps[s] = acc;
  }
  __syncthreads();

  // solve: thread (si = tid>>5, sg = tid&31)
  const int si = tid >> 5, sg = tid & 31;
  for (int blk = 0; blk < NB; ++blk) {
    float acc = 0.0f;
    const float* grow = Gb + (long)(blk * 32 + si) * 512;
    const int nq = (blk + 3) >> 2;
    for (int q = 0; q < nq; ++q) {
      const int c = (sg << 2) + (q << 7);
      if (c < blk * 32) {
        const float4 gv = *(const float4*)(grow + c);
        acc += gv.x * ds[c] + gv.y * ds[c + 1] + gv.z * ds[c + 2] + gv.w * ds[c + 3];
      }
    }
    part[si][sg] = acc;
    __syncthreads();
    if (tid < 32) {
      float s8 = 0.0f;
#pragma unroll
      for (int k = 0; k < 32; ++k) s8 += part[tid][k];
      rhs[tid] = ps[blk * 32 + tid] - CF * s8;
    }
    __syncthreads();
    part[si][sg] = Wl[blk][si][sg] * rhs[sg];
    __syncthreads();
    if (tid < 32) {
      float dv = 0.0f;
#pragma unroll
      for (int k = 0; k < 32; ++k) dv += part[tid][k];
      if (blk == NB - 1 && tid == 31) dv = 0.0f;   // dummy s=511
      ds[blk * 32 + tid] = dv;
    }
    __syncthreads();
  }

  {  // m[c] = CF * sum_t ds[510-t] * h[t][c]  — 4 t-chunks
    const int c = tid & 255, q4 = tid >> 8;
    float acc = 0.0f;
    const int t0 = q4 << 7;
    for (int t = t0; t < t0 + 128; ++t)
      if (t < 511) acc = fmaf(ds[510 - t], hb[(long)t * Hz + c], acc);
    pm[q4][c] = acc;
  }
  __syncthreads();
  if (tid < 256) ms[tid] = CF * (pm[0][tid] + pm[1][tid] + pm[2][tid] + pm[3][tid]);
  __syncthreads();
  {  // r[c] = ms @ Wrp + brp  — 4 e-chunks
    const int c = tid & 255, eq = tid >> 8;
    float acc = 0.0f;
#pragma unroll 8
    for (int e = eq * 64; e < eq * 64 + 64; ++e)
      acc = fmaf(ms[e], Wrp[(long)e * Hz + c], acc);
    pm[eq][c] = acc;
  }
  __syncthreads();
  if (tid < 256)
    r[b * Hz + tid] = pm[0][tid] + pm[1][tid] + pm[2][tid] + pm[3][tid] + brp[tid];
}

// ---------------------------------------------------------------------------
// out[8,32000] = r[8,256] @ Wout[256,32000] + bout.
// ---------------------------------------------------------------------------
__global__ __launch_bounds__(256) void k_outproj(
    const float* __restrict__ r, const float* __restrict__ Wout,
    const float* __restrict__ bout, float* __restrict__ out)
{
  __shared__ float rs[8 * Hz];
  __shared__ float part[4][8][64];
  const int tid = threadIdx.x, w = tid >> 6, lane = tid & 63;
  ((float4*)rs)[tid * 2 + 0] = ((const float4*)r)[tid * 2 + 0];
  ((float4*)rs)[tid * 2 + 1] = ((const float4*)r)[tid * 2 + 1];
  __syncthreads();
  const int col = blockIdx.x * 64 + lane;
  float acc[8] = {};
  const int i0 = w << 6;
#pragma unroll 8
  for (int ii = 0; ii < 64; ++ii) {
    const int i = i0 + ii;
    const float wv = Wout[(long)i * Vz + col];
#pragma unroll
    for (int bb = 0; bb < 8; ++bb) acc[bb] = fmaf(rs[bb * Hz + i], wv, acc[bb]);
  }
#pragma unroll
  for (int bb = 0; bb < 8; ++bb) part[w][bb][lane] = acc[bb];
  __syncthreads();
  const float bo = bout[col];
  float s0 = part[0][w][lane] + part[1][w][lane] + part[2][w][lane] + part[3][w][lane];
  out[(long)w * Vz + col] = s0 + bo;
  const int w4 = w + 4;
  float s1 = part[0][w4][lane] + part[1][w4][lane] + part[2][w4][lane] + part[3][w4][lane];
  out[(long)w4 * Vz + col] = s1 + bo;
}

// ---------------------------------------------------------------------------
extern "C" void kernel_launch(void* const* d_in, const int* in_sizes, int n_in,
                              void* d_out, int out_size, void* d_ws, size_t ws_size,
                              hipStream_t stream)
{
  const int*   seq   = (const int*)  d_in[0];
  const float* embed = (const float*)d_in[1];
  const float* W1    = (const float*)d_in[2];
  const float* b1    = (const float*)d_in[3];
  const float* W2    = (const float*)d_in[4];
  const float* b2    = (const float*)d_in[5];
  const float* gamma = (const float*)d_in[6];
  const float* beta  = (const float*)d_in[7];
  const float* Wrp   = (const float*)d_in[8];
  const float* brp   = (const float*)d_in[9];
  const float* Wout  = (const float*)d_in[10];
  const float* bout  = (const float*)d_in[11];
  float* out = (float*)d_out;

  char* ws = (char*)d_ws;
  const size_t MB = 1024u * 1024u;
  // Temporal overlay: y1bf/xb die before Gf is written (k_gramT runs after k_ln).
  short* y1bf = (short*)(ws);                        // 4 MB  [0,4)
  float* xb   = (float*)(ws + 4 * MB);               // 4 MB  [4,8)
  float* Gf   = (float*)(ws);                        // 8 MB  [0,8)  (after ln)
  float* hb   = (float*)(ws + 8 * MB);               // 4 MB
  float* hnb  = (float*)(ws + 12 * MB);              // 4 MB
  short* Knb  = (short*)(ws + 16 * MB);              // 2 MB  bf16 s-order keys
  short* Wt1  = (short*)(ws + 18 * MB);              // 256 KB
  short* Wt2  = (short*)(ws + 18 * MB + 256 * 1024); // 256 KB
  float* Wsol = (float*)(ws + 18 * MB + 512 * 1024); // 512 KB
  float* rb   = (float*)(ws + 19 * MB);              // 8 KB

  k_wcvt2<<<64, 256, 0, stream>>>(W1, W2, Wt1, Wt2);
  k_mfma1<<<dim3(H2z / 64, Mz / 64), 256, 0, stream>>>(seq, embed, Wt1, b1, y1bf);
  k_mfma2<<<dim3(Hz / 64, Mz / 64), 256, 0, stream>>>(seq, embed, y1bf, Wt2, b2, xb);
  k_ln<<<Mz / 4, 256, 0, stream>>>(xb, gamma, beta, hb, hnb, Knb);
  k_gramT<<<dim3(8, 8, Bz), 256, 0, stream>>>(Knb, Gf, Wsol);
  k_tail<<<Bz, 1024, 0, stream>>>(hb, hnb, Gf, Wsol, Wrp, brp, rb);
  k_outproj<<<Vz / 64, 256, 0, stream>>>(rb, Wout, bout, out);
}

// Round 9
// 200.735 us; speedup vs baseline: 1.0299x; 1.0299x over previous
//
#include <hip/hip_runtime.h>

// Problem constants
constexpr int Bz  = 8;
constexpr int Lz  = 512;
constexpr int Hz  = 256;
constexpr int H2z = 512;
constexpr int Vz  = 32000;
constexpr int Mz  = Bz * Lz;      // 4096 tokens
constexpr float CF = 0.05f;       // 1 - ALPHA
constexpr int NB  = 16;           // 16 blocks of 32 = 512 (511 real + 1 dummy)

typedef __attribute__((ext_vector_type(8))) short bfrag8;   // 8 bf16
typedef __attribute__((ext_vector_type(4))) float f32x4v;
typedef __attribute__((ext_vector_type(4))) short s4v;

static __device__ __forceinline__ short f2bf(float f) {
  unsigned u = __builtin_bit_cast(unsigned, f);
  u += 0x7fffu + ((u >> 16) & 1u);           // round-to-nearest-even
  return (short)(u >> 16);
}

// ---------------------------------------------------------------------------
// Weight transpose+convert, both W1 and W2 in one launch. dst[n][k]=bf16(src[k][n])
// ---------------------------------------------------------------------------
static __device__ __forceinline__ void wcvt_tile(
    const float* __restrict__ src, short* __restrict__ dst,
    int K, int N, int n0, int k0, int tid)
{
  __shared__ float tile[64][68];
  const int rr = tid >> 4, c4 = (tid & 15) << 2;
#pragma unroll
  for (int q = 0; q < 4; ++q) {
    const int kr = rr + q * 16;
    *(float4*)&tile[kr][c4] = *(const float4*)(src + (long)(k0 + kr) * N + n0 + c4);
  }
  __syncthreads();
#pragma unroll
  for (int q = 0; q < 4; ++q) {
    const int nr = rr + q * 16;
    s4v o = { f2bf(tile[c4 + 0][nr]), f2bf(tile[c4 + 1][nr]),
              f2bf(tile[c4 + 2][nr]), f2bf(tile[c4 + 3][nr]) };
    *(s4v*)(dst + (long)(n0 + nr) * K + k0 + c4) = o;
  }
}

__global__ __launch_bounds__(256) void k_wcvt2(
    const float* __restrict__ W1, const float* __restrict__ W2,
    short* __restrict__ Wt1, short* __restrict__ Wt2)
{
  const int bx = blockIdx.x, tid = threadIdx.x;
  if (bx < 32) {
    wcvt_tile(W1, Wt1, Hz, H2z, (bx & 7) * 64, (bx >> 3) * 64, tid);
  } else {
    const int b2 = bx - 32;
    wcvt_tile(W2, Wt2, H2z, Hz, (b2 & 3) * 64, (b2 >> 2) * 64, tid);
  }
}

// ---------------------------------------------------------------------------
// MFMA GEMM1 with fused embedding gather:
// y1bf[4096,512] = bf16(relu(bf16(embed[seq]) @ Wt1^T + b1))
// ---------------------------------------------------------------------------
__global__ __launch_bounds__(256) void k_mfma1(
    const int* __restrict__ seq, const float* __restrict__ embed,
    const short* __restrict__ Wt1, const float* __restrict__ b1,
    short* __restrict__ y1bf)
{
  __shared__ short As[64][32];
  __shared__ short Bs[64][32];
  const int tid = threadIdx.x;
  const int n0 = blockIdx.x * 64, m0 = blockIdx.y * 64;
  const int w = tid >> 6, l = tid & 63;
  const int srow = tid >> 2, skq = (tid & 3) << 3;
  const long abase = (long)seq[m0 + srow] * Hz;
  const f32x4v zero = {0.f, 0.f, 0.f, 0.f};
  f32x4v acc[4] = {zero, zero, zero, zero};
  for (int kc = 0; kc < Hz; kc += 32) {
    const float4 a0 = *(const float4*)(embed + abase + kc + skq);
    const float4 a1 = *(const float4*)(embed + abase + kc + skq + 4);
    const bfrag8 bvl = *(const bfrag8*)(Wt1 + (long)(n0 + srow) * Hz + kc + skq);
    __syncthreads();
    bfrag8 av = { f2bf(a0.x), f2bf(a0.y), f2bf(a0.z), f2bf(a0.w),
                  f2bf(a1.x), f2bf(a1.y), f2bf(a1.z), f2bf(a1.w) };
    *(bfrag8*)&As[srow][skq] = av;
    *(bfrag8*)&Bs[srow][skq] = bvl;
    __syncthreads();
    const bfrag8 a = *(const bfrag8*)&As[(w << 4) + (l & 15)][(l >> 4) << 3];
#pragma unroll
    for (int nn = 0; nn < 4; ++nn) {
      const bfrag8 bb = *(const bfrag8*)&Bs[(nn << 4) + (l & 15)][(l >> 4) << 3];
      acc[nn] = __builtin_amdgcn_mfma_f32_16x16x32_bf16(a, bb, acc[nn], 0, 0, 0);
    }
  }
  const int col0 = l & 15, quad = l >> 4;
#pragma unroll
  for (int nn = 0; nn < 4; ++nn) {
    const int col = n0 + (nn << 4) + col0;
    const float bias = b1[col];
#pragma unroll
    for (int i = 0; i < 4; ++i) {
      const int row = m0 + (w << 4) + (quad << 2) + i;
      y1bf[(long)row * H2z + col] = f2bf(fmaxf(acc[nn][i] + bias, 0.0f));
    }
  }
}

// ---------------------------------------------------------------------------
// MFMA GEMM2: x[4096,256] = y1bf @ Wt2^T + b2 + embed[seq]  (fp32 out)
// ---------------------------------------------------------------------------
__global__ __launch_bounds__(256) void k_mfma2(
    const int* __restrict__ seq, const float* __restrict__ embed,
    const short* __restrict__ y1bf, const short* __restrict__ Wt2,
    const float* __restrict__ b2, float* __restrict__ x)
{
  __shared__ short As[64][32];
  __shared__ short Bs[64][32];
  const int tid = threadIdx.x;
  const int n0 = blockIdx.x * 64, m0 = blockIdx.y * 64;
  const int w = tid >> 6, l = tid & 63;
  const int srow = tid >> 2, skq = (tid & 3) << 3;
  const f32x4v zero = {0.f, 0.f, 0.f, 0.f};
  f32x4v acc[4] = {zero, zero, zero, zero};
  for (int kc = 0; kc < H2z; kc += 32) {
    __syncthreads();
    *(bfrag8*)&As[srow][skq] = *(const bfrag8*)(y1bf + (long)(m0 + srow) * H2z + kc + skq);
    *(bfrag8*)&Bs[srow][skq] = *(const bfrag8*)(Wt2 + (long)(n0 + srow) * H2z + kc + skq);
    __syncthreads();
    const bfrag8 a = *(const bfrag8*)&As[(w << 4) + (l & 15)][(l >> 4) << 3];
#pragma unroll
    for (int nn = 0; nn < 4; ++nn) {
      const bfrag8 bb = *(const bfrag8*)&Bs[(nn << 4) + (l & 15)][(l >> 4) << 3];
      acc[nn] = __builtin_amdgcn_mfma_f32_16x16x32_bf16(a, bb, acc[nn], 0, 0, 0);
    }
  }
  const int col0 = l & 15, quad = l >> 4;
#pragma unroll
  for (int i = 0; i < 4; ++i) {
    const int row = m0 + (w << 4) + (quad << 2) + i;
    const long ebase = (long)seq[row] * Hz;
#pragma unroll
    for (int nn = 0; nn < 4; ++nn) {
      const int col = n0 + (nn << 4) + col0;
      x[(long)row * Hz + col] = acc[nn][i] + b2[col] + embed[ebase + col];
    }
  }
}

// ---------------------------------------------------------------------------
// LayerNorm + L2-normalize; writes h (fp32, t-order), hn (fp32, t-order),
// and Knb (bf16, s-order: s = 510-t; row 511 zeroed dummy).
// ---------------------------------------------------------------------------
__global__ __launch_bounds__(256) void k_ln(
    const float* __restrict__ x, const float* __restrict__ gamma,
    const float* __restrict__ beta, float* __restrict__ h,
    float* __restrict__ hn, short* __restrict__ Knb)
{
  const int lane = threadIdx.x & 63;
  const long row = (long)blockIdx.x * 4 + (threadIdx.x >> 6);
  const int b = (int)(row >> 9), t = (int)(row & 511);
  const int off = lane << 2;
  const float4 xv = *(const float4*)(x + row * Hz + off);
  float s  = xv.x + xv.y + xv.z + xv.w;
  float ss = xv.x * xv.x + xv.y * xv.y + xv.z * xv.z + xv.w * xv.w;
#pragma unroll
  for (int o = 32; o >= 1; o >>= 1) { s += __shfl_xor(s, o); ss += __shfl_xor(ss, o); }
  const float mu   = s * (1.0f / Hz);
  const float var  = ss * (1.0f / Hz) - mu * mu;
  const float rstd = rsqrtf(var + 1e-5f);
  const float4 gv = *(const float4*)(gamma + off);
  const float4 bv = *(const float4*)(beta + off);
  float4 hv;
  hv.x = (xv.x - mu) * rstd * gv.x + bv.x;
  hv.y = (xv.y - mu) * rstd * gv.y + bv.y;
  hv.z = (xv.z - mu) * rstd * gv.z + bv.z;
  hv.w = (xv.w - mu) * rstd * gv.w + bv.w;
  *(float4*)(h + row * Hz + off) = hv;
  float hs = hv.x * hv.x + hv.y * hv.y + hv.z * hv.z + hv.w * hv.w;
#pragma unroll
  for (int o = 32; o >= 1; o >>= 1) hs += __shfl_xor(hs, o);
  const float inv = 1.0f / fmaxf(sqrtf(hs), 1e-12f);
  float4 nv = {hv.x * inv, hv.y * inv, hv.z * inv, hv.w * inv};
  *(float4*)(hn + row * Hz + off) = nv;
  if (t < 511) {
    const int sidx = 510 - t;
    s4v o = { f2bf(nv.x), f2bf(nv.y), f2bf(nv.z), f2bf(nv.w) };
    *(s4v*)(Knb + ((long)b * 512 + sidx) * Hz + off) = o;
  } else {
    s4v z = {0, 0, 0, 0};
    *(s4v*)(Knb + ((long)b * 512 + 511) * Hz + off) = z;
  }
}

// ---------------------------------------------------------------------------
// Full Gram via bf16 MFMA (lower tiles), with FUSED block-diag inverse
// (one wave per 32x32 diag block, fully unrolled, no cross-lane ops).
// ---------------------------------------------------------------------------
__global__ __launch_bounds__(256) void k_gramT(
    const short* __restrict__ Knb, float* __restrict__ G,
    float* __restrict__ Wsol)
{
  const int nb = blockIdx.x, mb = blockIdx.y, b = blockIdx.z;
  if (nb > mb) return;
  __shared__ short As[64][32];
  __shared__ short Bs[64][32];
  __shared__ float Gs2[2][32][33];
  const short* Kb = Knb + (long)b * 512 * Hz;
  const int tid = threadIdx.x;
  const int w = tid >> 6, l = tid & 63;
  const int srow = tid >> 2, skq = (tid & 3) << 3;
  const f32x4v zero = {0.f, 0.f, 0.f, 0.f};
  f32x4v acc[4] = {zero, zero, zero, zero};
  for (int kc = 0; kc < Hz; kc += 32) {
    __syncthreads();
    *(bfrag8*)&As[srow][skq] = *(const bfrag8*)(Kb + (long)(mb * 64 + srow) * Hz + kc + skq);
    *(bfrag8*)&Bs[srow][skq] = *(const bfrag8*)(Kb + (long)(nb * 64 + srow) * Hz + kc + skq);
    __syncthreads();
    const bfrag8 a = *(const bfrag8*)&As[(w << 4) + (l & 15)][(l >> 4) << 3];
#pragma unroll
    for (int nn = 0; nn < 4; ++nn) {
      const bfrag8 bb = *(const bfrag8*)&Bs[(nn << 4) + (l & 15)][(l >> 4) << 3];
      acc[nn] = __builtin_amdgcn_mfma_f32_16x16x32_bf16(a, bb, acc[nn], 0, 0, 0);
    }
  }
  const int col0 = l & 15, quad = l >> 4;
  float* Gb = G + (long)b * 512 * 512;
#pragma unroll
  for (int nn = 0; nn < 4; ++nn) {
    const int col = nb * 64 + (nn << 4) + col0;
#pragma unroll
    for (int i = 0; i < 4; ++i) {
      const int row = mb * 64 + (w << 4) + (quad << 2) + i;
      Gb[(long)row * 512 + col] = acc[nn][i];
    }
  }
  if (mb != nb) return;
#pragma unroll
  for (int nn = 0; nn < 4; ++nn) {
    const int lc = (nn << 4) + col0;
#pragma unroll
    for (int i = 0; i < 4; ++i) {
      const int lr = (w << 4) + (quad << 2) + i;
      if ((lr >> 5) == (lc >> 5)) Gs2[lr >> 5][lr & 31][lc & 31] = acc[nn][i];
    }
  }
  __syncthreads();
  if (w < 2 && l < 32) {       // wave w inverts sub-block w; lane = column c
    const int c = l;
    float wv[32];
    wv[0] = (c == 0) ? 1.0f : 0.0f;
#pragma unroll
    for (int i = 1; i < 32; ++i) {
      float sum = 0.0f;
#pragma unroll
      for (int j = 0; j < i; ++j) sum = fmaf(Gs2[w][i][j], wv[j], sum);
      wv[i] = ((i == c) ? 1.0f : 0.0f) - CF * sum;
    }
    const int blk = mb * 2 + w;
    float* dst = Wsol + ((long)(b * NB + blk) << 10) + c;
#pragma unroll
    for (int i = 0; i < 32; ++i) dst[i * 32] = wv[i];
  }
}

// ---------------------------------------------------------------------------
// p[b][s] = hn[b][510-s] . h[b][511]  (fp32).  16 s-rows per WG, 256 WGs.
// ---------------------------------------------------------------------------
__global__ __launch_bounds__(256) void k_p(
    const float* __restrict__ h, const float* __restrict__ hn,
    float* __restrict__ p)
{
  __shared__ float qs[Hz];
  const int b = blockIdx.y, tid = threadIdx.x;
  qs[tid] = h[((long)b * Lz + 511) * Hz + tid];
  __syncthreads();
  const int s = blockIdx.x * 16 + (tid >> 4);
  const int ch = (tid & 15) << 4;
  float acc = 0.0f;
  if (s <= 510) {
    const float* src = hn + ((long)b * Lz + (510 - s)) * Hz + ch;
#pragma unroll
    for (int q = 0; q < 4; ++q) {
      const float4 v = *(const float4*)(src + 4 * q);
      acc += v.x * qs[ch + 4 * q] + v.y * qs[ch + 4 * q + 1] +
             v.z * qs[ch + 4 * q + 2] + v.w * qs[ch + 4 * q + 3];
    }
  }
#pragma unroll
  for (int o = 8; o >= 1; o >>= 1) acc += __shfl_xor(acc, o);
  if ((tid & 15) == 0) p[(long)b * 512 + s] = acc;
}

// ---------------------------------------------------------------------------
// Block-triangular solve — only the truly-serial chain. 8 WGs x 256 thr.
// ---------------------------------------------------------------------------
__global__ __launch_bounds__(256) void k_solve(
    const float* __restrict__ G, const float* __restrict__ p,
    const float* __restrict__ Wsol, float* __restrict__ d_all)
{
  __shared__ float ds[512];
  __shared__ float part[32][9];
  __shared__ float rhs[32];
  const int b = blockIdx.x, tid = threadIdx.x;
  const int i = tid >> 3, g = tid & 7;
  const float* Gb = G + (long)b * 512 * 512;
  const float* pb = p + (long)b * 512;

  for (int blk = 0; blk < NB; ++blk) {
    float acc0 = 0.0f, acc1 = 0.0f;
    const float* grow = Gb + (long)(blk * 32 + i) * 512 + (g << 2);
    int bp = 0;
    for (; bp + 1 < blk; bp += 2) {
      const float4 g0 = *(const float4*)(grow + bp * 32);
      const float4 g1 = *(const float4*)(grow + bp * 32 + 32);
      const int j0 = bp * 32 + (g << 2), j1 = j0 + 32;
      acc0 += g0.x * ds[j0] + g0.y * ds[j0 + 1] + g0.z * ds[j0 + 2] + g0.w * ds[j0 + 3];
      acc1 += g1.x * ds[j1] + g1.y * ds[j1 + 1] + g1.z * ds[j1 + 2] + g1.w * ds[j1 + 3];
    }
    if (bp < blk) {
      const float4 gv = *(const float4*)(grow + bp * 32);
      const int j = bp * 32 + (g << 2);
      acc0 += gv.x * ds[j] + gv.y * ds[j + 1] + gv.z * ds[j + 2] + gv.w * ds[j + 3];
    }
    part[i][g] = acc0 + acc1;
    __syncthreads();
    if (tid < 32) {
      float c = part[tid][0] + part[tid][1] + part[tid][2] + part[tid][3] +
                part[tid][4] + part[tid][5] + part[tid][6] + part[tid][7];
      rhs[tid] = pb[blk * 32 + tid] - CF * c;
    }
    __syncthreads();
    const float* wrow = Wsol + ((long)(b * NB + blk) << 10) + i * 32 + (g << 2);
    const float4 wv = *(const float4*)wrow;
    const int k0 = g << 2;
    part[i][g] = wv.x * rhs[k0] + wv.y * rhs[k0 + 1] +
                 wv.z * rhs[k0 + 2] + wv.w * rhs[k0 + 3];
    __syncthreads();
    if (tid < 32) {
      float dv = part[tid][0] + part[tid][1] + part[tid][2] + part[tid][3] +
                 part[tid][4] + part[tid][5] + part[tid][6] + part[tid][7];
      if (blk == NB - 1 && tid == 31) dv = 0.0f;   // dummy s=511
      ds[blk * 32 + tid] = dv;
      d_all[(long)b * 512 + blk * 32 + tid] = dv;
    }
    __syncthreads();
  }
}

// ---------------------------------------------------------------------------
// m partials, float4-vectorized: chunk c covers 16 t; wave w handles
// t = t0 + {w, w+4, w+8, w+12}; lane loads dwordx4 of the h row.
// part[b][c][:] accumulated across the 4 waves via LDS.
// ---------------------------------------------------------------------------
__global__ __launch_bounds__(256) void k_mrp(
    const float* __restrict__ h, const float* __restrict__ d_all,
    float* __restrict__ part)
{
  __shared__ float acc_s[4][Hz];
  const int c = blockIdx.x, b = blockIdx.y, tid = threadIdx.x;
  const int w = tid >> 6, lane = tid & 63;
  const float* hb = h + (long)b * Lz * Hz;
  const float* db = d_all + ((long)b << 9);
  const int t0 = c * 16;
  const int off = lane << 2;
  float4 acc = {0.f, 0.f, 0.f, 0.f};
#pragma unroll
  for (int q = 0; q < 4; ++q) {
    const int t = t0 + (q << 2) + w;
    if (t < 511) {
      const float dv = db[510 - t];
      const float4 hv = *(const float4*)(hb + (long)t * Hz + off);
      acc.x = fmaf(dv, hv.x, acc.x); acc.y = fmaf(dv, hv.y, acc.y);
      acc.z = fmaf(dv, hv.z, acc.z); acc.w = fmaf(dv, hv.w, acc.w);
    }
  }
  *(float4*)&acc_s[w][off] = acc;
  __syncthreads();
  if (tid < Hz) {
    part[((long)b * 32 + c) * Hz + tid] =
        acc_s[0][tid] + acc_s[1][tid] + acc_s[2][tid] + acc_s[3][tid];
  }
}

// ---------------------------------------------------------------------------
// Combine partials -> m; r = m @ Wrp + brp.  8 WGs.
// ---------------------------------------------------------------------------
__global__ __launch_bounds__(256) void k_mr2(
    const float* __restrict__ part, const float* __restrict__ Wrp,
    const float* __restrict__ brp, float* __restrict__ r)
{
  __shared__ float ms[Hz];
  const int b = blockIdx.x, tid = threadIdx.x;
  float acc = 0.0f;
#pragma unroll
  for (int c = 0; c < 32; ++c) acc += part[((long)b * 32 + c) * Hz + tid];
  ms[tid] = CF * acc;
  __syncthreads();
  float racc = 0.0f;
#pragma unroll 8
  for (int e = 0; e < Hz; ++e)
    racc = fmaf(ms[e], Wrp[(long)e * Hz + tid], racc);
  r[b * Hz + tid] = racc + brp[tid];
}

// ---------------------------------------------------------------------------
// out[8,32000] = r[8,256] @ Wout[256,32000] + bout.
// ---------------------------------------------------------------------------
__global__ __launch_bounds__(256) void k_outproj(
    const float* __restrict__ r, const float* __restrict__ Wout,
    const float* __restrict__ bout, float* __restrict__ out)
{
  __shared__ float rs[8 * Hz];
  __shared__ float part[4][8][64];
  const int tid = threadIdx.x, w = tid >> 6, lane = tid & 63;
  ((float4*)rs)[tid * 2 + 0] = ((const float4*)r)[tid * 2 + 0];
  ((float4*)rs)[tid * 2 + 1] = ((const float4*)r)[tid * 2 + 1];
  __syncthreads();
  const int col = blockIdx.x * 64 + lane;
  float acc[8] = {};
  const int i0 = w << 6;
#pragma unroll 8
  for (int ii = 0; ii < 64; ++ii) {
    const int i = i0 + ii;
    const float wv = Wout[(long)i * Vz + col];
#pragma unroll
    for (int bb = 0; bb < 8; ++bb) acc[bb] = fmaf(rs[bb * Hz + i], wv, acc[bb]);
  }
#pragma unroll
  for (int bb = 0; bb < 8; ++bb) part[w][bb][lane] = acc[bb];
  __syncthreads();
  const float bo = bout[col];
  float s0 = part[0][w][lane] + part[1][w][lane] + part[2][w][lane] + part[3][w][lane];
  out[(long)w * Vz + col] = s0 + bo;
  const int w4 = w + 4;
  float s1 = part[0][w4][lane] + part[1][w4][lane] + part[2][w4][lane] + part[3][w4][lane];
  out[(long)w4 * Vz + col] = s1 + bo;
}

// ---------------------------------------------------------------------------
extern "C" void kernel_launch(void* const* d_in, const int* in_sizes, int n_in,
                              void* d_out, int out_size, void* d_ws, size_t ws_size,
                              hipStream_t stream)
{
  const int*   seq   = (const int*)  d_in[0];
  const float* embed = (const float*)d_in[1];
  const float* W1    = (const float*)d_in[2];
  const float* b1    = (const float*)d_in[3];
  const float* W2    = (const float*)d_in[4];
  const float* b2    = (const float*)d_in[5];
  const float* gamma = (const float*)d_in[6];
  const float* beta  = (const float*)d_in[7];
  const float* Wrp   = (const float*)d_in[8];
  const float* brp   = (const float*)d_in[9];
  const float* Wout  = (const float*)d_in[10];
  const float* bout  = (const float*)d_in[11];
  float* out = (float*)d_out;

  char* ws = (char*)d_ws;
  const size_t MB = 1024u * 1024u;
  // Temporal overlay: y1bf/xb die before Gf is written (k_gramT runs after k_ln).
  short* y1bf = (short*)(ws);                        // 4 MB  [0,4)
  float* xb   = (float*)(ws + 4 * MB);               // 4 MB  [4,8)
  float* Gf   = (float*)(ws);                        // 8 MB  [0,8)  (after ln)
  float* hb   = (float*)(ws + 8 * MB);               // 4 MB
  float* hnb  = (float*)(ws + 12 * MB);              // 4 MB
  short* Knb  = (short*)(ws + 16 * MB);              // 2 MB  bf16 s-order keys
  short* Wt1  = (short*)(ws + 18 * MB);              // 256 KB
  short* Wt2  = (short*)(ws + 18 * MB + 256 * 1024); // 256 KB
  float* Wsol = (float*)(ws + 18 * MB + 512 * 1024); // 512 KB
  float* pbuf = (float*)(ws + 19 * MB);                        // 16 KB
  float* dall = (float*)(ws + 19 * MB + 16 * 1024);            // 16 KB
  float* prt  = (float*)(ws + 19 * MB + 32 * 1024);            // 256 KB
  float* rb   = (float*)(ws + 19 * MB + 288 * 1024);           // 8 KB

  k_wcvt2<<<64, 256, 0, stream>>>(W1, W2, Wt1, Wt2);
  k_mfma1<<<dim3(H2z / 64, Mz / 64), 256, 0, stream>>>(seq, embed, Wt1, b1, y1bf);
  k_mfma2<<<dim3(Hz / 64, Mz / 64), 256, 0, stream>>>(seq, embed, y1bf, Wt2, b2, xb);
  k_ln<<<Mz / 4, 256, 0, stream>>>(xb, gamma, beta, hb, hnb, Knb);
  k_gramT<<<dim3(8, 8, Bz), 256, 0, stream>>>(Knb, Gf, Wsol);
  k_p<<<dim3(32, Bz), 256, 0, stream>>>(hb, hnb, pbuf);
  k_solve<<<Bz, 256, 0, stream>>>(Gf, pbuf, Wsol, dall);
  k_mrp<<<dim3(32, Bz), 256, 0, stream>>>(hb, dall, prt);
  k_mr2<<<Bz, 256, 0, stream>>>(prt, Wrp, brp, rb);
  k_outproj<<<Vz / 64, 256, 0, stream>>>(rb, Wout, bout, out);
}